// Round 7
// baseline (184.709 us; speedup 1.0000x reference)
//
#include <hip/hip_runtime.h>
#include <hip/hip_bf16.h>

#define TOKENS 2048
#define FDIM 512
#define HDIM 2048
#define NEXP 8
#define PI_F 3.14159265358979323846f

typedef __attribute__((ext_vector_type(8))) short bf16x8;
typedef __attribute__((ext_vector_type(4))) float f32x4;

__device__ __forceinline__ unsigned short f2bf(float f) {
  unsigned int u = __float_as_uint(f);
  unsigned int r = (u + 0x7fffu + ((u >> 16) & 1u)) >> 16;
  return (unsigned short)r;
}

__device__ __forceinline__ void gload16(const void* g, void* l) {
  __builtin_amdgcn_global_load_lds(
      (const __attribute__((address_space(1))) unsigned int*)g,
      (__attribute__((address_space(3))) unsigned int*)l, 16, 0, 0);
}

__device__ __forceinline__ unsigned cvtpk_bf16(float a, float b) {
  unsigned r;
  asm("v_cvt_pk_bf16_f32 %0, %1, %2" : "=v"(r) : "v"(a), "v"(b));
  return r;   // lo16 = bf16(a), hi16 = bf16(b)
}

// ---------------- routing ----------------
__global__ __launch_bounds__(256) void route_kernel(
    const float* __restrict__ xr, const float* __restrict__ xi,
    int* __restrict__ idx, int* __restrict__ counts)
{
  int tid = threadIdx.x;
  int t = blockIdx.x * 8 + (tid >> 5);
  int l = tid & 31;
  const float* r  = xr + (size_t)t * FDIM;
  const float* im = xi + (size_t)t * FDIM;
  float sc = 0.f, ss = 0.f;
  #pragma unroll
  for (int p = 0; p < 4; ++p) {
    int f = p * 128 + l * 4;
    float4 a4 = *(const float4*)(r + f);
    float4 b4 = *(const float4*)(im + f);
    float av[4] = {a4.x, a4.y, a4.z, a4.w};
    float bv[4] = {b4.x, b4.y, b4.z, b4.w};
    #pragma unroll
    for (int j = 0; j < 4; ++j) {
      float h2 = av[j] * av[j] + bv[j] * bv[j];
      if (h2 > 0.f) {
        float rs = rsqrtf(h2);
        sc += av[j] * rs;
        ss += bv[j] * rs;
      } else {
        sc += 1.f;   // atan2(0,0)=0 -> cos=1, sin=0
      }
    }
  }
  #pragma unroll
  for (int off = 16; off > 0; off >>= 1) {
    sc += __shfl_down(sc, off, 32);
    ss += __shfl_down(ss, off, 32);
  }
  if (l == 0) {
    float phase = atan2f(ss, sc);
    float norm = (phase + PI_F) / (2.f * PI_F);
    int e = (int)floorf(norm * (float)NEXP);
    e = min(max(e, 0), NEXP - 1);
    idx[t] = e;
    atomicAdd(&counts[e], 1);
  }
}

// deterministic scatter: perm within each expert in ascending token order
__global__ __launch_bounds__(256) void scatter_kernel(
    const int* __restrict__ idx, const int* __restrict__ counts,
    int* __restrict__ offs, int* __restrict__ perm, int* __restrict__ rexp)
{
  __shared__ int base_e[NEXP];
  __shared__ int tcnt[256][NEXP];
  int tid = threadIdx.x;
  if (tid == 0) {
    int acc = 0;
    for (int e = 0; e < NEXP; ++e) { base_e[e] = acc; offs[e] = acc; acc += counts[e]; }
  }
  int t0 = tid * 8;
  int eo[8];
  int loc[NEXP];
  #pragma unroll
  for (int e = 0; e < NEXP; ++e) loc[e] = 0;
  #pragma unroll
  for (int j = 0; j < 8; ++j) { eo[j] = idx[t0 + j]; loc[eo[j]]++; }
  #pragma unroll
  for (int e = 0; e < NEXP; ++e) tcnt[tid][e] = loc[e];
  __syncthreads();
  if (tid < NEXP) {
    int e = tid, run = 0;
    for (int i = 0; i < 256; ++i) { int v = tcnt[i][e]; tcnt[i][e] = run; run += v; }
  }
  __syncthreads();
  #pragma unroll
  for (int e = 0; e < NEXP; ++e) loc[e] = base_e[e] + tcnt[tid][e];
  #pragma unroll
  for (int j = 0; j < 8; ++j) {
    int e = eo[j];
    int pos = loc[e]++;
    perm[pos] = t0 + j;
    rexp[pos] = e;
  }
}

// ---------------- packing x ----------------
__global__ __launch_bounds__(256) void pack_x_kernel(
    const float* __restrict__ xr, const float* __restrict__ xi,
    const int* __restrict__ perm,
    short* __restrict__ Ar, short* __restrict__ Ai)
{
  int gid = blockIdx.x * 256 + threadIdx.x;   // 2048 * 128
  int i = gid >> 7;
  int c4 = (gid & 127) * 4;
  int tok = perm[i];
  float4 r = *(const float4*)(xr + (size_t)tok * FDIM + c4);
  float4 m = *(const float4*)(xi + (size_t)tok * FDIM + c4);
  unsigned short orr[4] = { f2bf(r.x), f2bf(r.y), f2bf(r.z), f2bf(r.w) };
  unsigned short oii[4] = { f2bf(m.x), f2bf(m.y), f2bf(m.z), f2bf(m.w) };
  *(int2*)(Ar + (size_t)i * FDIM + c4) = *(const int2*)orr;
  *(int2*)(Ai + (size_t)i * FDIM + c4) = *(const int2*)oii;
}

// ---------------- plane-separated complex MFMA grouped GEMM ----------------
// A planes [2048][LDKA] bf16 compact; W global fp32 [E][Ktot][NC] (n contig).
// W converted+transposed in-kernel: quad DPP 4x4 transpose -> Ws[n][k] bf16.
// BM=128 x 64 complex cols, BK=32, 4 waves (2x2), wave-tile 64x32c.
// Block map (per expert, 128 blocks): rem = ((x<<SB)|s)<<2 | y (y innermost
// so same-W-slice blocks run together on the expert's XCD -> L2 reuse).
template<int LDKA, int NC, int SB, bool IS_L1>
__global__ __launch_bounds__(256) void gemm_cplx(
    const short* __restrict__ Apr, const short* __restrict__ Api,
    const float* __restrict__ Wrg, const float* __restrict__ Wig,
    const int* __restrict__ counts, const int* __restrict__ offs,
    const float* __restrict__ bre, const float* __restrict__ bim,
    const float* __restrict__ mb,
    short* __restrict__ Or, short* __restrict__ Oi, float* __restrict__ P)
{
  constexpr int KT = 16;                     // 16 x BK=32 = 512 K-chunk
  int bid = blockIdx.x;
  int virt = (bid & 7) * 128 + (bid >> 3);   // expert e -> XCD e
  int e = virt >> 7, rem = virt & 127;
  int y = rem & 3;
  int s = (rem >> 2) & ((1 << SB) - 1);      // SB=0 -> s=0
  int x = rem >> (2 + SB);
  int cnt = counts[e];
  int row0 = y * 128;
  if (row0 >= cnt) return;
  int base = offs[e];
  int n0c = x * 64;
  int kb = s * 512;

  __shared__ __align__(16) short As[2][2][128][32];  // [buf][plane][row][k] 32KB
  __shared__ __align__(16) short Ws[2][2][64][32];   // 16KB

  int tid = threadIdx.x;
  int lane = tid & 63;
  int w = tid >> 6, wm = w >> 1, wn = w & 1;
  int lr = lane & 15, g = lane >> 4;
  int ssw = g ^ ((lr >> 1) & 3);             // swizzled 16B slot for reads

  // ---- A staging (gload16, source pre-swizzled; verified r6) ----
  int srl = tid >> 2, slt = tid & 3;
  int sc = (slt ^ ((srl >> 1) & 3)) * 16;
  const char* pA[2][2];
  #pragma unroll
  for (int rg = 0; rg < 2; ++rg) {
    int arow = min(row0 + rg * 64 + srl, cnt - 1);
    pA[rg][0] = (const char*)(Apr + (size_t)(base + arow) * LDKA + kb) + sc;
    pA[rg][1] = (const char*)(Api + (size_t)(base + arow) * LDKA + kb) + sc;
  }
  auto STAGE_A = [&](int buf, int t) {
    char* ab = (char*)&As[buf][0][0][0];
    gload16(pA[0][0] + t * 64, ab + tid * 16);
    gload16(pA[1][0] + t * 64, ab + 4096 + tid * 16);
    gload16(pA[0][1] + t * 64, ab + 8192 + tid * 16);
    gload16(pA[1][1] + t * 64, ab + 12288 + tid * 16);
  };

  // ---- W staging (fp32 -> bf16 + quad 4x4 transpose via DPP) ----
  int q   = tid & 3;                // row within quad (k low bits)
  int tn  = (tid >> 2) & 15;        // n-quad index
  int khi = tid >> 6;               // k slot (8k per slot)
  int nloc = tn * 4 + q;            // LDS n-row this thread writes
  unsigned psel = (q & 1) ? 0x03020706u : 0x05040100u;
  bool qlow = (q & 2) == 0;
  int wofs = nloc * 32 + ((khi ^ ((nloc >> 1) & 3)) * 8);   // shorts
  const float* wr0 = Wrg + ((size_t)e * (IS_L1 ? FDIM : HDIM) + kb + 8 * khi + q) * NC + (n0c + tn * 4);
  const float* wi0 = Wig + ((size_t)e * (IS_L1 ? FDIM : HDIM) + kb + 8 * khi + q) * NC + (n0c + tn * 4);

  auto qtr = [&](uint2 Y) -> uint2 {
    int Tx = __builtin_amdgcn_update_dpp((int)Y.x, (int)Y.x, 0x4E, 0xF, 0xF, false); // xor2
    int Ty = __builtin_amdgcn_update_dpp((int)Y.y, (int)Y.y, 0x4E, 0xF, 0xF, false);
    unsigned Ux = qlow ? Y.x : (unsigned)Ty;
    unsigned Uy = qlow ? (unsigned)Tx : Y.y;
    int t2x = __builtin_amdgcn_update_dpp((int)Ux, (int)Ux, 0xB1, 0xF, 0xF, false);  // xor1
    int t2y = __builtin_amdgcn_update_dpp((int)Uy, (int)Uy, 0xB1, 0xF, 0xF, false);
    uint2 Z;
    Z.x = __builtin_amdgcn_perm((unsigned)t2x, Ux, psel);
    Z.y = __builtin_amdgcn_perm((unsigned)t2y, Uy, psel);
    return Z;
  };
  auto W_FIN = [&](int buf, float4 r0, float4 r1, float4 i0, float4 i1) {
    uint2 Yr0 = {cvtpk_bf16(r0.x, r0.y), cvtpk_bf16(r0.z, r0.w)};
    uint2 Yr1 = {cvtpk_bf16(r1.x, r1.y), cvtpk_bf16(r1.z, r1.w)};
    uint2 Yi0 = {cvtpk_bf16(i0.x, i0.y), cvtpk_bf16(i0.z, i0.w)};
    uint2 Yi1 = {cvtpk_bf16(i1.x, i1.y), cvtpk_bf16(i1.z, i1.w)};
    uint2 Zr0 = qtr(Yr0), Zr1 = qtr(Yr1), Zi0 = qtr(Yi0), Zi1 = qtr(Yi1);
    short* wb = &Ws[buf][0][0][0];
    int4 vr = {(int)Zr0.x, (int)Zr0.y, (int)Zr1.x, (int)Zr1.y};   // k slot khi: 8k
    int4 vi = {(int)Zi0.x, (int)Zi0.y, (int)Zi1.x, (int)Zi1.y};
    *(int4*)(wb + wofs) = vr;
    *(int4*)(wb + 2048 + wofs) = vi;
  };

  f32x4 accr[4][2], acci[4][2];
  #pragma unroll
  for (int m = 0; m < 4; ++m)
    #pragma unroll
    for (int n = 0; n < 2; ++n) { accr[m][n] = 0.f; acci[m][n] = 0.f; }

  const bf16x8 SGN = {(short)0x8000, (short)0x8000, (short)0x8000, (short)0x8000,
                      (short)0x8000, (short)0x8000, (short)0x8000, (short)0x8000};

  auto COMPUTE = [&](int buf) {
    const short* Ab = &As[buf][0][0][0];
    const short* Wb = &Ws[buf][0][0][0];
    bf16x8 ar[4], ai[4], wr[2], wi[2], wni[2];
    #pragma unroll
    for (int m = 0; m < 4; ++m) {
      int off = (wm * 64 + m * 16 + lr) * 32 + ssw * 8;
      ar[m] = *(const bf16x8*)(Ab + off);
      ai[m] = *(const bf16x8*)(Ab + 4096 + off);
    }
    #pragma unroll
    for (int n = 0; n < 2; ++n) {
      int offw = (wn * 32 + n * 16 + lr) * 32 + ssw * 8;
      wr[n] = *(const bf16x8*)(Wb + offw);
      wi[n] = *(const bf16x8*)(Wb + 2048 + offw);
      wni[n] = wi[n] ^ SGN;
    }
    #pragma unroll
    for (int m = 0; m < 4; ++m)
      #pragma unroll
      for (int n = 0; n < 2; ++n) {
        accr[m][n] = __builtin_amdgcn_mfma_f32_16x16x32_bf16(ar[m], wr[n],  accr[m][n], 0, 0, 0);
        accr[m][n] = __builtin_amdgcn_mfma_f32_16x16x32_bf16(ai[m], wni[n], accr[m][n], 0, 0, 0);
        acci[m][n] = __builtin_amdgcn_mfma_f32_16x16x32_bf16(ar[m], wi[n],  acci[m][n], 0, 0, 0);
        acci[m][n] = __builtin_amdgcn_mfma_f32_16x16x32_bf16(ai[m], wr[n],  acci[m][n], 0, 0, 0);
      }
  };

  // prologue: stage tile 0 (both A and W)
  {
    float4 r0 = *(const float4*)(wr0);
    float4 r1 = *(const float4*)(wr0 + 4 * (size_t)NC);
    float4 i0 = *(const float4*)(wi0);
    float4 i1 = *(const float4*)(wi0 + 4 * (size_t)NC);
    STAGE_A(0, 0);
    W_FIN(0, r0, r1, i0, i1);
  }
  int cur = 0;
  for (int t = 0; t < KT; ++t) {
    __syncthreads();                          // tile `cur` fully staged (vm+lgkm)
    bool pf = (t + 1 < KT);
    float4 r0, r1, i0, i1;
    if (pf) {
      size_t ro = (size_t)(t + 1) * 32 * NC;
      r0 = *(const float4*)(wr0 + ro);        // issue early: hide under MFMA
      r1 = *(const float4*)(wr0 + ro + 4 * (size_t)NC);
      i0 = *(const float4*)(wi0 + ro);
      i1 = *(const float4*)(wi0 + ro + 4 * (size_t)NC);
      STAGE_A(cur ^ 1, t + 1);
    }
    COMPUTE(cur);
    if (pf) W_FIN(cur ^ 1, r0, r1, i0, i1);   // cvt+transpose+write after MFMA
    cur ^= 1;
  }

  // epilogue
  #pragma unroll
  for (int m = 0; m < 4; ++m) {
    #pragma unroll
    for (int qq = 0; qq < 4; ++qq) {
      int row = row0 + wm * 64 + m * 16 + g * 4 + qq;
      if (row >= cnt) continue;
      #pragma unroll
      for (int n = 0; n < 2; ++n) {
        int c = n0c + wn * 32 + n * 16 + lr;
        if constexpr (IS_L1) {
          float hr = accr[m][n][qq] + bre[e * NC + c];
          float hi = acci[m][n][qq] + bim[e * NC + c];
          float s2 = hr * hr + hi * hi + 1e-10f;
          float rr = __frsqrt_rn(s2);
          float amp = s2 * rr;
          float scl = fmaxf(amp + mb[e * NC + c], 0.f) * rr;
          Or[(size_t)(base + row) * NC + c] = (short)f2bf(hr * scl);
          Oi[(size_t)(base + row) * NC + c] = (short)f2bf(hi * scl);
        } else {
          float* Pr = P + ((size_t)s * TOKENS + base + row) * 1024;
          Pr[c] = accr[m][n][qq];
          Pr[512 + c] = acci[m][n][qq];
        }
      }
    }
  }
}

// ---------------- split-K finalize ----------------
__global__ __launch_bounds__(256) void finalize_kernel(
    const float* __restrict__ P, const float* __restrict__ br2,
    const float* __restrict__ bi2, const int* __restrict__ perm,
    const int* __restrict__ rexp, float* __restrict__ out)
{
  int gid = blockIdx.x * 256 + threadIdx.x;   // 2048 * 128
  int i = gid >> 7;
  int c4 = (gid & 127) * 4;
  float4 vr = *(const float4*)(P + (size_t)i * 1024 + c4);
  float4 vi = *(const float4*)(P + (size_t)i * 1024 + 512 + c4);
  #pragma unroll
  for (int s = 1; s < 4; ++s) {
    float4 ur = *(const float4*)(P + ((size_t)s * TOKENS + i) * 1024 + c4);
    float4 ui = *(const float4*)(P + ((size_t)s * TOKENS + i) * 1024 + 512 + c4);
    vr.x += ur.x; vr.y += ur.y; vr.z += ur.z; vr.w += ur.w;
    vi.x += ui.x; vi.y += ui.y; vi.z += ui.z; vi.w += ui.w;
  }
  int e = rexp[i], tok = perm[i];
  float4 br = *(const float4*)(br2 + e * FDIM + c4);
  float4 bi = *(const float4*)(bi2 + e * FDIM + c4);
  vr.x += br.x; vr.y += br.y; vr.z += br.z; vr.w += br.w;
  vi.x += bi.x; vi.y += bi.y; vi.z += bi.z; vi.w += bi.w;
  *(float4*)(out + (size_t)tok * FDIM + c4) = vr;
  *(float4*)(out + (size_t)TOKENS * FDIM + (size_t)tok * FDIM + c4) = vi;
}

extern "C" void kernel_launch(void* const* d_in, const int* in_sizes, int n_in,
                              void* d_out, int out_size, void* d_ws, size_t ws_size,
                              hipStream_t stream)
{
  const float* xr  = (const float*)d_in[0];
  const float* xi  = (const float*)d_in[1];
  const float* Wr1 = (const float*)d_in[2];
  const float* Wi1 = (const float*)d_in[3];
  const float* br1 = (const float*)d_in[4];
  const float* bi1 = (const float*)d_in[5];
  const float* mb  = (const float*)d_in[6];
  const float* Wr2 = (const float*)d_in[7];
  const float* Wi2 = (const float*)d_in[8];
  const float* br2 = (const float*)d_in[9];
  const float* bi2 = (const float*)d_in[10];
  float* out = (float*)d_out;

  char* ws = (char*)d_ws;
  int* counts = (int*)(ws + 0);
  int* offs   = (int*)(ws + 64);
  int* idx    = (int*)(ws + 128);
  int* perm   = (int*)(ws + 8320);
  int* rexp   = (int*)(ws + 16512);

  size_t off = 32768;
  short* A1r = (short*)(ws + off); off += (size_t)TOKENS * FDIM * 2;
  short* A1i = (short*)(ws + off); off += (size_t)TOKENS * FDIM * 2;
  short* A2r = (short*)(ws + off); off += (size_t)TOKENS * HDIM * 2;
  short* A2i = (short*)(ws + off); off += (size_t)TOKENS * HDIM * 2;
  float* P   = (float*)(ws + off);

  hipMemsetAsync(counts, 0, 64, stream);
  route_kernel<<<TOKENS / 8, 256, 0, stream>>>(xr, xi, idx, counts);
  scatter_kernel<<<1, 256, 0, stream>>>(idx, counts, offs, perm, rexp);
  pack_x_kernel<<<TOKENS * 128 / 256, 256, 0, stream>>>(xr, xi, perm, A1r, A1i);

  // layer1: K=512, NC=2048 -> A2 planes (bias+ModReLU fused), W from fp32
  gemm_cplx<FDIM, HDIM, 0, true><<<1024, 256, 0, stream>>>(
      A1r, A1i, Wr1, Wi1, counts, offs, br1, bi1, mb, A2r, A2i, nullptr);
  // layer2: K=2048 split 4x512, NC=512 -> P partials, W from fp32
  gemm_cplx<HDIM, FDIM, 2, false><<<1024, 256, 0, stream>>>(
      A2r, A2i, Wr2, Wi2, counts, offs, nullptr, nullptr, nullptr,
      nullptr, nullptr, P);

  finalize_kernel<<<TOKENS * 128 / 256, 256, 0, stream>>>(
      P, br2, bi2, perm, rexp, out);
}

// Round 8
// 154.597 us; speedup vs baseline: 1.1948x; 1.1948x over previous
//
#include <hip/hip_runtime.h>
#include <hip/hip_bf16.h>

#define TOKENS 2048
#define FDIM 512
#define HDIM 2048
#define NEXP 8
#define PI_F 3.14159265358979323846f

typedef __attribute__((ext_vector_type(8))) short bf16x8;
typedef __attribute__((ext_vector_type(4))) float f32x4;

__device__ __forceinline__ unsigned short f2bf(float f) {
  unsigned int u = __float_as_uint(f);
  unsigned int r = (u + 0x7fffu + ((u >> 16) & 1u)) >> 16;
  return (unsigned short)r;
}

__device__ __forceinline__ void gload16(const void* g, void* l) {
  __builtin_amdgcn_global_load_lds(
      (const __attribute__((address_space(1))) unsigned int*)g,
      (__attribute__((address_space(3))) unsigned int*)l, 16, 0, 0);
}

// ---------------- routing (r7: 8 tokens/block, width-32 reduce) ----------------
__global__ __launch_bounds__(256) void route_kernel(
    const float* __restrict__ xr, const float* __restrict__ xi,
    int* __restrict__ idx, int* __restrict__ counts)
{
  int tid = threadIdx.x;
  int t = blockIdx.x * 8 + (tid >> 5);
  int l = tid & 31;
  const float* r  = xr + (size_t)t * FDIM;
  const float* im = xi + (size_t)t * FDIM;
  float sc = 0.f, ss = 0.f;
  #pragma unroll
  for (int p = 0; p < 4; ++p) {
    int f = p * 128 + l * 4;
    float4 a4 = *(const float4*)(r + f);
    float4 b4 = *(const float4*)(im + f);
    float av[4] = {a4.x, a4.y, a4.z, a4.w};
    float bv[4] = {b4.x, b4.y, b4.z, b4.w};
    #pragma unroll
    for (int j = 0; j < 4; ++j) {
      float h2 = av[j] * av[j] + bv[j] * bv[j];
      if (h2 > 0.f) {
        float rs = rsqrtf(h2);
        sc += av[j] * rs;
        ss += bv[j] * rs;
      } else {
        sc += 1.f;   // atan2(0,0)=0 -> cos=1, sin=0
      }
    }
  }
  #pragma unroll
  for (int off = 16; off > 0; off >>= 1) {
    sc += __shfl_down(sc, off, 32);
    ss += __shfl_down(ss, off, 32);
  }
  if (l == 0) {
    float phase = atan2f(ss, sc);
    float norm = (phase + PI_F) / (2.f * PI_F);
    int e = (int)floorf(norm * (float)NEXP);
    e = min(max(e, 0), NEXP - 1);
    idx[t] = e;
    atomicAdd(&counts[e], 1);
  }
}

// deterministic scatter: perm within each expert in ascending token order
__global__ __launch_bounds__(256) void scatter_kernel(
    const int* __restrict__ idx, const int* __restrict__ counts,
    int* __restrict__ offs, int* __restrict__ perm, int* __restrict__ rexp)
{
  __shared__ int base_e[NEXP];
  __shared__ int tcnt[256][NEXP];
  int tid = threadIdx.x;
  if (tid == 0) {
    int acc = 0;
    for (int e = 0; e < NEXP; ++e) { base_e[e] = acc; offs[e] = acc; acc += counts[e]; }
  }
  int t0 = tid * 8;
  int eo[8];
  int loc[NEXP];
  #pragma unroll
  for (int e = 0; e < NEXP; ++e) loc[e] = 0;
  #pragma unroll
  for (int j = 0; j < 8; ++j) { eo[j] = idx[t0 + j]; loc[eo[j]]++; }
  #pragma unroll
  for (int e = 0; e < NEXP; ++e) tcnt[tid][e] = loc[e];
  __syncthreads();
  if (tid < NEXP) {
    int e = tid, run = 0;
    for (int i = 0; i < 256; ++i) { int v = tcnt[i][e]; tcnt[i][e] = run; run += v; }
  }
  __syncthreads();
  #pragma unroll
  for (int e = 0; e < NEXP; ++e) loc[e] = base_e[e] + tcnt[tid][e];
  #pragma unroll
  for (int j = 0; j < 8; ++j) {
    int e = eo[j];
    int pos = loc[e]++;
    perm[pos] = t0 + j;
    rexp[pos] = e;
  }
}

// ---------------- packing ----------------
__global__ __launch_bounds__(256) void pack_x_kernel(
    const float* __restrict__ xr, const float* __restrict__ xi,
    const int* __restrict__ perm,
    short* __restrict__ Ar, short* __restrict__ Ai)
{
  int gid = blockIdx.x * 256 + threadIdx.x;   // 2048 * 128
  int i = gid >> 7;
  int c4 = (gid & 127) * 4;
  int tok = perm[i];
  float4 r = *(const float4*)(xr + (size_t)tok * FDIM + c4);
  float4 m = *(const float4*)(xi + (size_t)tok * FDIM + c4);
  unsigned short orr[4] = { f2bf(r.x), f2bf(r.y), f2bf(r.z), f2bf(r.w) };
  unsigned short oii[4] = { f2bf(m.x), f2bf(m.y), f2bf(m.z), f2bf(m.w) };
  *(int2*)(Ar + (size_t)i * FDIM + c4) = *(const int2*)orr;
  *(int2*)(Ai + (size_t)i * FDIM + c4) = *(const int2*)oii;
}

// r5-proven: W[e][K][N] fp32 (r,i) -> Wp[e][2][N][K] bf16 (plane0=Wr^T, 1=Wi^T)
template<int K, int N>
__global__ __launch_bounds__(256) void pack_w_kernel(
    const float* __restrict__ Wr, const float* __restrict__ Wi,
    short* __restrict__ Wp)
{
  int e = blockIdx.z;
  int k0 = blockIdx.y * 32, n0 = blockIdx.x * 32;
  __shared__ float tr[32][33], ti[32][33];
  int tid = threadIdx.x;
  int row = tid >> 3, c4 = (tid & 7) * 4;
  const float* wr = Wr + ((size_t)e * K + k0) * N + n0;
  const float* wi = Wi + ((size_t)e * K + k0) * N + n0;
  float4 vr = *(const float4*)(wr + (size_t)row * N + c4);
  float4 vi = *(const float4*)(wi + (size_t)row * N + c4);
  *(float4*)&tr[row][c4] = vr;
  *(float4*)&ti[row][c4] = vi;
  __syncthreads();
  int nl = tid >> 3, k4 = (tid & 7) * 4;
  unsigned short pr[4], pi[4];
  #pragma unroll
  for (int j = 0; j < 4; ++j) {
    pr[j] = f2bf(tr[k4 + j][nl]);
    pi[j] = f2bf(ti[k4 + j][nl]);
  }
  size_t b0 = (((size_t)e * 2 + 0) * N + n0 + nl) * K + k0 + k4;
  size_t b1 = (((size_t)e * 2 + 1) * N + n0 + nl) * K + k0 + k4;
  *(int2*)(Wp + b0) = *(const int2*)pr;
  *(int2*)(Wp + b1) = *(const int2*)pi;
}

// ---------------- plane-separated complex MFMA grouped GEMM (r6-proven) ------
// BM=128 x BNc=64, BK=32, 4 waves (2x2), wave-tile 64x32c (MF=4, NF=2).
// Single-barrier-per-step dbuf. 128 blocks per expert, expert -> XCD.
template<int LDK, int NC, int NX, bool IS_L1>
__global__ __launch_bounds__(256) void gemm_cplx(
    const short* __restrict__ Apr, const short* __restrict__ Api,
    const short* __restrict__ Wp,
    const int* __restrict__ counts, const int* __restrict__ offs,
    const float* __restrict__ bre, const float* __restrict__ bim,
    const float* __restrict__ mb,
    short* __restrict__ Or, short* __restrict__ Oi, float* __restrict__ P)
{
  constexpr int KT = 16;                     // 16 x BK=32 = 512 K-chunk
  int bid = blockIdx.x;
  int virt = (bid & 7) * 128 + (bid >> 3);   // expert e -> XCD e
  int e = virt >> 7, rem = virt & 127;
  int x = rem % NX;
  int q = rem / NX;
  int y = q & 3, s = q >> 2;                 // IS_L1: q<4 -> s=0
  int cnt = counts[e];
  int row0 = y * 128;
  if (row0 >= cnt) return;
  int base = offs[e];
  int n0c = x * 64;
  int kbase = s * 512;

  __shared__ __align__(16) short As[2][2][128][32];  // [buf][plane][row][k]
  __shared__ __align__(16) short Ws[2][2][64][32];

  int tid = threadIdx.x;
  int lane = tid & 63;
  int w = tid >> 6, wm = w >> 1, wn = w & 1;
  int lr = lane & 15, g = lane >> 4;
  int ssw = g ^ ((lr >> 1) & 3);             // swizzled 16B slot for reads

  int srl = tid >> 2, slt = tid & 3;
  int sc = (slt ^ ((srl >> 1) & 3)) * 16;    // pre-swizzled source byte offset
  const char* pA[2][2];
  #pragma unroll
  for (int rg = 0; rg < 2; ++rg) {
    int arow = min(row0 + rg * 64 + srl, cnt - 1);
    pA[rg][0] = (const char*)(Apr + (size_t)(base + arow) * LDK + kbase) + sc;
    pA[rg][1] = (const char*)(Api + (size_t)(base + arow) * LDK + kbase) + sc;
  }
  const short* We = Wp + (size_t)e * 2 * NC * LDK;
  const char* pW0 = (const char*)(We + (size_t)(n0c + srl) * LDK + kbase) + sc;
  const char* pW1 = (const char*)(We + ((size_t)NC + n0c + srl) * LDK + kbase) + sc;

  auto STAGE = [&](int buf, int t) {
    char* ab = (char*)&As[buf][0][0][0];
    gload16(pA[0][0] + t * 64, ab + tid * 16);
    gload16(pA[1][0] + t * 64, ab + 4096 + tid * 16);
    gload16(pA[0][1] + t * 64, ab + 8192 + tid * 16);
    gload16(pA[1][1] + t * 64, ab + 12288 + tid * 16);
    char* wb = (char*)&Ws[buf][0][0][0];
    gload16(pW0 + t * 64, wb + tid * 16);
    gload16(pW1 + t * 64, wb + 4096 + tid * 16);
  };

  f32x4 accr[4][2], acci[4][2];
  #pragma unroll
  for (int m = 0; m < 4; ++m)
    #pragma unroll
    for (int n = 0; n < 2; ++n) { accr[m][n] = 0.f; acci[m][n] = 0.f; }

  const bf16x8 SGN = {(short)0x8000, (short)0x8000, (short)0x8000, (short)0x8000,
                      (short)0x8000, (short)0x8000, (short)0x8000, (short)0x8000};

  auto COMPUTE = [&](int buf) {
    const short* Ab = &As[buf][0][0][0];
    const short* Wb = &Ws[buf][0][0][0];
    bf16x8 ar[4], ai[4], wr[2], wi[2], wni[2];
    #pragma unroll
    for (int m = 0; m < 4; ++m) {
      int off = (wm * 64 + m * 16 + lr) * 32 + ssw * 8;
      ar[m] = *(const bf16x8*)(Ab + off);
      ai[m] = *(const bf16x8*)(Ab + 4096 + off);
    }
    #pragma unroll
    for (int n = 0; n < 2; ++n) {
      int offw = (wn * 32 + n * 16 + lr) * 32 + ssw * 8;
      wr[n] = *(const bf16x8*)(Wb + offw);
      wi[n] = *(const bf16x8*)(Wb + 2048 + offw);
      wni[n] = wi[n] ^ SGN;
    }
    #pragma unroll
    for (int m = 0; m < 4; ++m)
      #pragma unroll
      for (int n = 0; n < 2; ++n) {
        accr[m][n] = __builtin_amdgcn_mfma_f32_16x16x32_bf16(ar[m], wr[n],  accr[m][n], 0, 0, 0);
        accr[m][n] = __builtin_amdgcn_mfma_f32_16x16x32_bf16(ai[m], wni[n], accr[m][n], 0, 0, 0);
        acci[m][n] = __builtin_amdgcn_mfma_f32_16x16x32_bf16(ar[m], wi[n],  acci[m][n], 0, 0, 0);
        acci[m][n] = __builtin_amdgcn_mfma_f32_16x16x32_bf16(ai[m], wr[n],  acci[m][n], 0, 0, 0);
      }
  };

  STAGE(0, 0);
  int cur = 0;
  for (int t = 0; t < KT; ++t) {
    __syncthreads();                         // stage of `cur` drained (vm+lgkm)
    if (t + 1 < KT) STAGE(cur ^ 1, t + 1);   // prefetch in flight across MFMA
    COMPUTE(cur);
    cur ^= 1;
  }

  // epilogue
  #pragma unroll
  for (int m = 0; m < 4; ++m) {
    #pragma unroll
    for (int qq = 0; qq < 4; ++qq) {
      int row = row0 + wm * 64 + m * 16 + g * 4 + qq;
      if (row >= cnt) continue;
      #pragma unroll
      for (int n = 0; n < 2; ++n) {
        int c = n0c + wn * 32 + n * 16 + lr;
        if constexpr (IS_L1) {
          float hr = accr[m][n][qq] + bre[e * NC + c];
          float hi = acci[m][n][qq] + bim[e * NC + c];
          float s2 = hr * hr + hi * hi + 1e-10f;
          float rr = __frsqrt_rn(s2);
          float amp = s2 * rr;
          float scl = fmaxf(amp + mb[e * NC + c], 0.f) * rr;
          Or[(size_t)(base + row) * NC + c] = (short)f2bf(hr * scl);
          Oi[(size_t)(base + row) * NC + c] = (short)f2bf(hi * scl);
        } else {
          float* Pr = P + ((size_t)s * TOKENS + base + row) * 1024;
          Pr[c] = accr[m][n][qq];
          Pr[512 + c] = acci[m][n][qq];
        }
      }
    }
  }
}

// ---------------- split-K finalize ----------------
__global__ __launch_bounds__(256) void finalize_kernel(
    const float* __restrict__ P, const float* __restrict__ br2,
    const float* __restrict__ bi2, const int* __restrict__ perm,
    const int* __restrict__ rexp, float* __restrict__ out)
{
  int gid = blockIdx.x * 256 + threadIdx.x;   // 2048 * 128
  int i = gid >> 7;
  int c4 = (gid & 127) * 4;
  float4 vr = *(const float4*)(P + (size_t)i * 1024 + c4);
  float4 vi = *(const float4*)(P + (size_t)i * 1024 + 512 + c4);
  #pragma unroll
  for (int s = 1; s < 4; ++s) {
    float4 ur = *(const float4*)(P + ((size_t)s * TOKENS + i) * 1024 + c4);
    float4 ui = *(const float4*)(P + ((size_t)s * TOKENS + i) * 1024 + 512 + c4);
    vr.x += ur.x; vr.y += ur.y; vr.z += ur.z; vr.w += ur.w;
    vi.x += ui.x; vi.y += ui.y; vi.z += ui.z; vi.w += ui.w;
  }
  int e = rexp[i], tok = perm[i];
  float4 br = *(const float4*)(br2 + e * FDIM + c4);
  float4 bi = *(const float4*)(bi2 + e * FDIM + c4);
  vr.x += br.x; vr.y += br.y; vr.z += br.z; vr.w += br.w;
  vi.x += bi.x; vi.y += bi.y; vi.z += bi.z; vi.w += bi.w;
  *(float4*)(out + (size_t)tok * FDIM + c4) = vr;
  *(float4*)(out + (size_t)TOKENS * FDIM + (size_t)tok * FDIM + c4) = vi;
}

extern "C" void kernel_launch(void* const* d_in, const int* in_sizes, int n_in,
                              void* d_out, int out_size, void* d_ws, size_t ws_size,
                              hipStream_t stream)
{
  const float* xr  = (const float*)d_in[0];
  const float* xi  = (const float*)d_in[1];
  const float* Wr1 = (const float*)d_in[2];
  const float* Wi1 = (const float*)d_in[3];
  const float* br1 = (const float*)d_in[4];
  const float* bi1 = (const float*)d_in[5];
  const float* mb  = (const float*)d_in[6];
  const float* Wr2 = (const float*)d_in[7];
  const float* Wi2 = (const float*)d_in[8];
  const float* br2 = (const float*)d_in[9];
  const float* bi2 = (const float*)d_in[10];
  float* out = (float*)d_out;

  char* ws = (char*)d_ws;
  int* counts = (int*)(ws + 0);
  int* offs   = (int*)(ws + 64);
  int* idx    = (int*)(ws + 128);
  int* perm   = (int*)(ws + 8320);
  int* rexp   = (int*)(ws + 16512);

  size_t off = 32768;
  short* A1r = (short*)(ws + off); off += (size_t)TOKENS * FDIM * 2;
  short* A1i = (short*)(ws + off); off += (size_t)TOKENS * FDIM * 2;
  short* A2r = (short*)(ws + off); off += (size_t)TOKENS * HDIM * 2;
  short* A2i = (short*)(ws + off); off += (size_t)TOKENS * HDIM * 2;
  short* W1p = (short*)(ws + off); off += (size_t)NEXP * 2 * HDIM * FDIM * 2;
  short* W2p = (short*)(ws + off); off += (size_t)NEXP * 2 * FDIM * HDIM * 2;
  float* P   = (float*)(ws + off);

  hipMemsetAsync(counts, 0, 64, stream);
  route_kernel<<<TOKENS / 8, 256, 0, stream>>>(xr, xi, idx, counts);
  scatter_kernel<<<1, 256, 0, stream>>>(idx, counts, offs, perm, rexp);

  pack_x_kernel<<<TOKENS * 128 / 256, 256, 0, stream>>>(xr, xi, perm, A1r, A1i);
  pack_w_kernel<FDIM, HDIM><<<dim3(HDIM / 32, FDIM / 32, NEXP), 256, 0, stream>>>(
      Wr1, Wi1, W1p);
  pack_w_kernel<HDIM, FDIM><<<dim3(FDIM / 32, HDIM / 32, NEXP), 256, 0, stream>>>(
      Wr2, Wi2, W2p);

  // layer1: K=512, NC=2048 (NX=32) -> A2 planes (bias+ModReLU fused)
  gemm_cplx<FDIM, HDIM, 32, true><<<1024, 256, 0, stream>>>(
      A1r, A1i, W1p, counts, offs, br1, bi1, mb, A2r, A2i, nullptr);
  // layer2: K=2048 split 4x512, NC=512 (NX=8) -> P partials
  gemm_cplx<HDIM, FDIM, 8, false><<<1024, 256, 0, stream>>>(
      A2r, A2i, W2p, counts, offs, nullptr, nullptr, nullptr, nullptr, nullptr, P);

  finalize_kernel<<<TOKENS * 128 / 256, 256, 0, stream>>>(
      P, br2, bi2, perm, rexp, out);
}